// Round 2
// baseline (18158.328 us; speedup 1.0000x reference)
//
#include <hip/hip_runtime.h>

// FixedPtSQP: 1024 independent SQP solves, N=64, M_IN=128 (G=[I;-I]), M_EQ=1 (A=1^T).
// One wave (64 lanes) per batch element; lane i owns row i of H=Q+diag(dd).
// R1: Q lives in LDS (not registers) so only ONE 64-float register array (Hrow)
// exists -> no scratch spills. Fast rcp/rsq everywhere (threshold 2e-2, we were at 2e-6).

#define QS 68   // Q row stride in LDS floats (16B-aligned rows for b128 reads)
#define LS 65   // L row stride: conflict-free b32 access by row AND column

__device__ __forceinline__ float frcp(float x) { return __builtin_amdgcn_rcpf(x); }
__device__ __forceinline__ float frsq(float x) { return __builtin_amdgcn_rsqf(x); }

__device__ __forceinline__ float wave_sum(float v) {
#pragma unroll
  for (int o = 32; o > 0; o >>= 1) v += __shfl_xor(v, o, 64);
  return v;
}
__device__ __forceinline__ float wave_min(float v) {
#pragma unroll
  for (int o = 32; o > 0; o >>= 1) v = fminf(v, __shfl_xor(v, o, 64));
  return v;
}

__global__ __launch_bounds__(64, 1) void sqp_solve_kernel(
    const float* __restrict__ C, const float* __restrict__ Q,
    float* __restrict__ out) {
  const int b = blockIdx.x;
  const int i = threadIdx.x;  // lane == row index

  __shared__ float Qlds[64 * QS];   // Q, row-major, stride 68
  __shared__ float Lmat[64 * LS];   // L (lower), stride 65
  __shared__ float rldiag[64];      // 1/L[k][k]
  __shared__ float colbuf[2][64];   // current Cholesky column (contiguous -> b128 bcast reads)
  __shared__ float bcast[64];       // vector broadcast scratch

  // Stage Q into LDS once (shared by all 6 SQP iters x 15 Newton iters)
#pragma unroll
  for (int j = 0; j < 64; j += 4) {
    const float4 q = *reinterpret_cast<const float4*>(&Q[i * 64 + j]);
    *reinterpret_cast<float4*>(&Qlds[i * QS + j]) = q;
  }
  const float ci = C[b * 64 + i];
  __syncthreads();

  float x = 0.5f;   // x0
  float d = 0.0f;   // last QP primal step

#pragma unroll 1
  for (int sqp = 0; sqp < 6; ++sqp) {   // MAX_ITER1 + MAX_ITER2, ALPHA=1
    // p = Q0 x - c  (Q0 symmetric)
    bcast[i] = x;
    __syncthreads();
    float p = -ci;
#pragma unroll
    for (int j = 0; j < 64; ++j) p = fmaf(Qlds[i * QS + j], bcast[j], p);
    const float h1 = 1.0f - x;
    const float h2 = x;
    const float beq = 1.0f - wave_sum(x);
    __syncthreads();

    // QP state (lane i holds z_i, s/lam halves i and 64+i, nu uniform)
    float z = 0.f, s1 = 1.f, s2 = 1.f, l1 = 1.f, l2 = 1.f, nu = 0.f;

#pragma unroll 1
    for (int it = 0; it < 15; ++it) {   // NEWTON_ITERS
      const float mu = 0.1f * wave_sum(fmaf(s1, l1, s2 * l2)) * (1.0f / 128.0f);

      // Load Q row i into the single register array; matvec Qz from it
      float Hrow[64];
#pragma unroll
      for (int j = 0; j < 64; j += 4) {
        const float4 q = *reinterpret_cast<const float4*>(&Qlds[i * QS + j]);
        Hrow[j + 0] = q.x; Hrow[j + 1] = q.y; Hrow[j + 2] = q.z; Hrow[j + 3] = q.w;
      }
      bcast[i] = z;
      __syncthreads();
      float Qz = 0.f;
#pragma unroll
      for (int j = 0; j < 64; ++j) Qz = fmaf(Hrow[j], bcast[j], Qz);

      const float rs1 = frcp(s1), rs2 = frcp(s2);
      const float r_dual = Qz + p + (l1 - l2) + nu;   // G^T lam = l1-l2; A^T nu = nu
      const float rp1 = z + s1 - h1;                  // G z = [z; -z]
      const float rp2 = -z + s2 - h2;
      const float r_peq = wave_sum(z) - beq;
      const float rc1 = fmaf(l1, s1, -mu);
      const float rc2 = fmaf(l2, s2, -mu);
      const float dd = fmaf(l1, rs1, l2 * rs2);       // diag of G^T D G
      const float w1 = (l1 * rp1 - rc1) * rs1;
      const float w2 = (l2 * rp2 - rc2) * rs2;
      const float rhs = -(r_dual + w1 - w2);          // rhs_z

      // H = Q + dd * e_i e_i^T (lane i adds dd at column i; compile-time select)
#pragma unroll
      for (int j = 0; j < 64; ++j) Hrow[j] += (j == i) ? dd : 0.0f;

      // In-place right-looking Cholesky; column k lives in Hrow[k] across lanes i>=k.
#pragma unroll
      for (int k = 0; k < 64; ++k) {
        const float akk = __shfl(Hrow[k], k, 64);
        const float rl = frsq(fmaxf(akk, 1e-30f));
        const float lik = Hrow[k] * rl;
        Hrow[k] = lik;                 // L[i][k] (valid for i>=k)
        colbuf[k & 1][i] = lik;
        Lmat[i * LS + k] = lik;        // persist L for the L^T solve (conflict-free)
        if (i == 0) rldiag[k] = rl;
        __syncthreads();
        const float* cb = colbuf[k & 1];
#pragma unroll
        for (int j = k + 1; j < 64; ++j)
          Hrow[j] = fmaf(-lik, cb[j], Hrow[j]);       // trailing rank-1 update
      }
      __syncthreads();

      // Forward solve L a = [rhs, 1] (two RHS fused)
      float a1 = rhs, a2 = 1.0f, y1 = 0.f, y2 = 0.f;
#pragma unroll
      for (int k = 0; k < 64; ++k) {
        const float rl = rldiag[k];
        const float t1 = __shfl(a1, k, 64) * rl;
        const float t2 = __shfl(a2, k, 64) * rl;
        if (i == k) { y1 = t1; y2 = t2; }
        const float lk = (i > k) ? Hrow[k] : 0.0f;    // L[i][k]
        a1 = fmaf(-lk, t1, a1);
        a2 = fmaf(-lk, t2, a2);
      }

      // Backward solve L^T u = y (two RHS); L[k][i] from LDS column (conflict-free)
      float u1 = 0.f, u2 = 0.f;
      a1 = y1; a2 = y2;
#pragma unroll
      for (int k = 63; k >= 0; --k) {
        const float rl = rldiag[k];
        const float t1 = __shfl(a1, k, 64) * rl;
        const float t2 = __shfl(a2, k, 64) * rl;
        if (i == k) { u1 = t1; u2 = t2; }
        const float lki = (i < k) ? Lmat[k * LS + i] : 0.0f;
        a1 = fmaf(-lki, t1, a1);
        a2 = fmaf(-lki, t2, a2);
      }

      // Bordered system: dnu = (1^T u1 + r_peq) / (1^T u2); dz = u1 - dnu*u2
      const float sum1 = wave_sum(u1);
      const float sum2 = wave_sum(u2);
      const float dnu = (sum1 + r_peq) * frcp(sum2);
      const float dz = fmaf(-dnu, u2, u1);

      const float dl1 = (l1 * (rp1 + dz) - rc1) * rs1;  // G dz = [dz; -dz]
      const float dl2 = (l2 * (rp2 - dz) - rc2) * rs2;
      const float ds1 = -rp1 - dz;
      const float ds2 = -rp2 + dz;

      const float c1m = (dl1 < 0.0f) ? (-l1 * frcp(dl1)) : 1.0f;
      const float c2m = (dl2 < 0.0f) ? (-l2 * frcp(dl2)) : 1.0f;
      const float c3m = (ds1 < 0.0f) ? (-s1 * frcp(ds1)) : 1.0f;
      const float c4m = (ds2 < 0.0f) ? (-s2 * frcp(ds2)) : 1.0f;
      const float am = wave_min(fminf(fminf(c1m, c2m), fminf(c3m, c4m)));
      const float a = 0.99f * fminf(1.0f, am);

      z = fmaf(a, dz, z);
      s1 = fmaf(a, ds1, s1);
      s2 = fmaf(a, ds2, s2);
      l1 = fmaf(a, dl1, l1);
      l2 = fmaf(a, dl2, l2);
      nu = fmaf(a, dnu, nu);
      __syncthreads();   // protect LDS (bcast/colbuf/Lmat) before next iteration rewrites
    }

    x += z;   // ALPHA=1; lam carried in reference but never read
    d = z;
  }

  out[b * 64 + i] = x + d;   // reference returns x + d

  (void)d;
}

extern "C" void kernel_launch(void* const* d_in, const int* in_sizes, int n_in,
                              void* d_out, int out_size, void* d_ws, size_t ws_size,
                              hipStream_t stream) {
  const float* c = (const float*)d_in[0];   // (B, 64) f32
  const float* Q = (const float*)d_in[1];   // (64, 64) f32
  float* out = (float*)d_out;               // (B, 64) f32
  const int B = in_sizes[0] / 64;
  hipLaunchKernelGGL(sqp_solve_kernel, dim3(B), dim3(64), 0, stream, c, Q, out);
}

// Round 3
// 1607.976 us; speedup vs baseline: 11.2927x; 11.2927x over previous
//
#include <hip/hip_runtime.h>

// FixedPtSQP: 1024 independent SQP solves, N=64, M_IN=128 (G=[I;-I]), M_EQ=1 (A=1^T).
// One wave per batch element; lane i owns row i of H = Q + diag(dd).
// R2: LDL^T (no sqrt, no rldiag) with the forward solve FUSED into the
// factorization loop so Hrow's live range ends before the backward solve.
// This kills the hoisted-load register pressure that was spilling to scratch
// (R0/R1: VGPR=256 + 30 GB scratch traffic).

#define QS 68   // Q row stride in LDS floats (rows 16B-aligned for b128 reads)
#define LS 65   // L row stride: conflict-free by row and by column

__device__ __forceinline__ float frcp(float x) { return __builtin_amdgcn_rcpf(x); }

__device__ __forceinline__ float wave_sum(float v) {
#pragma unroll
  for (int o = 32; o > 0; o >>= 1) v += __shfl_xor(v, o, 64);
  return v;
}
__device__ __forceinline__ float wave_min(float v) {
#pragma unroll
  for (int o = 32; o > 0; o >>= 1) v = fminf(v, __shfl_xor(v, o, 64));
  return v;
}

__global__ __launch_bounds__(64, 1) void sqp_solve_kernel(
    const float* __restrict__ C, const float* __restrict__ Q,
    float* __restrict__ out) {
  const int b = blockIdx.x;
  const int i = threadIdx.x;  // lane == row index

  __shared__ __align__(16) float Qlds[64 * QS];   // pristine Q
  __shared__ __align__(16) float Lmat[64 * LS];   // unit-lower L (strictly lower used)
  __shared__ __align__(16) float colbuf[2][64];   // unscaled Cholesky column w
  __shared__ __align__(16) float bcast[64];       // vector broadcast scratch

  // Stage Q into LDS once
#pragma unroll
  for (int j = 0; j < 64; j += 4) {
    const float4 q = *reinterpret_cast<const float4*>(&Q[i * 64 + j]);
    *reinterpret_cast<float4*>(&Qlds[i * QS + j]) = q;
  }
  const float ci = C[b * 64 + i];
  __syncthreads();

  float x = 0.5f;   // x0
  float d = 0.0f;   // last QP primal step

#pragma unroll 1
  for (int sqp = 0; sqp < 6; ++sqp) {   // MAX_ITER1 + MAX_ITER2, ALPHA=1
    // p = Q0 x - c  (Q0 symmetric), vectorized row read
    bcast[i] = x;
    __syncthreads();
    float p = -ci;
#pragma unroll
    for (int j = 0; j < 64; j += 4) {
      const float4 q = *reinterpret_cast<const float4*>(&Qlds[i * QS + j]);
      const float4 xv = *reinterpret_cast<const float4*>(&bcast[j]);
      p = fmaf(q.x, xv.x, p); p = fmaf(q.y, xv.y, p);
      p = fmaf(q.z, xv.z, p); p = fmaf(q.w, xv.w, p);
    }
    const float h1 = 1.0f - x;
    const float h2 = x;
    const float beq = 1.0f - wave_sum(x);
    __syncthreads();

    float z = 0.f, s1 = 1.f, s2 = 1.f, l1 = 1.f, l2 = 1.f, nu = 0.f;

#pragma unroll 1
    for (int it = 0; it < 15; ++it) {   // NEWTON_ITERS
      const float mu = 0.1f * wave_sum(fmaf(s1, l1, s2 * l2)) * (1.0f / 128.0f);

      // Fresh H row from pristine Q (b128), matvec Qz from registers
      float Hrow[64];
#pragma unroll
      for (int j = 0; j < 64; j += 4) {
        const float4 q = *reinterpret_cast<const float4*>(&Qlds[i * QS + j]);
        Hrow[j + 0] = q.x; Hrow[j + 1] = q.y; Hrow[j + 2] = q.z; Hrow[j + 3] = q.w;
      }
      bcast[i] = z;
      __syncthreads();
      float Qz = 0.f;
#pragma unroll
      for (int j = 0; j < 64; ++j) Qz = fmaf(Hrow[j], bcast[j], Qz);

      const float rs1 = frcp(s1), rs2 = frcp(s2);
      const float r_dual = Qz + p + (l1 - l2) + nu;
      const float rp1 = z + s1 - h1;
      const float rp2 = -z + s2 - h2;
      const float r_peq = wave_sum(z) - beq;
      const float rc1 = fmaf(l1, s1, -mu);
      const float rc2 = fmaf(l2, s2, -mu);
      const float dd = fmaf(l1, rs1, l2 * rs2);
      const float w1 = (l1 * rp1 - rc1) * rs1;
      const float w2 = (l2 * rp2 - rc2) * rs2;
      const float rhs = -(r_dual + w1 - w2);

#pragma unroll
      for (int j = 0; j < 64; ++j) Hrow[j] += (j == i) ? dd : 0.0f;

      // In-place LDL^T with fused forward solve on [rhs, 1].
      // Pivots d_k >= 1 (Q0 >= I, dd > 0) -> unguarded rcp is safe.
      float a1 = rhs, a2 = 1.0f, y1 = 0.f, y2 = 0.f, myrd = 0.f;
#pragma unroll
      for (int k = 0; k < 64; ++k) {
        const float akk = __shfl(Hrow[k], k, 64);   // pivot d_k (uniform)
        const float rd = frcp(akk);
        myrd = (i == k) ? rd : myrd;                // lane k keeps 1/d_k
        const float w = Hrow[k];                    // unscaled column entry w_i
        const float lik = w * rd;                   // L[i][k] (valid i>k)
        colbuf[k & 1][i] = w;
        Lmat[i * LS + k] = lik;
        // fused forward step (unit-diagonal L)
        const float t1 = __shfl(a1, k, 64);
        const float t2 = __shfl(a2, k, 64);
        y1 = (i == k) ? t1 : y1;
        y2 = (i == k) ? t2 : y2;
        const float likm = (i > k) ? lik : 0.0f;
        a1 = fmaf(-likm, t1, a1);
        a2 = fmaf(-likm, t2, a2);
        __syncthreads();
        // trailing update H[i][j] -= lik * w_j, j > k.
        // float4-aligned start; slots j<=k are dead (never read again) so
        // touching them is harmless and keeps every access a 16B broadcast.
        const float* cb = colbuf[k & 1];
        const int j0 = (k + 1) & ~3;
#pragma unroll
        for (int j = 0; j < 64; j += 4) {
          if (j >= j0) {
            const float4 wv = *reinterpret_cast<const float4*>(&cb[j]);
            Hrow[j + 0] = fmaf(-lik, wv.x, Hrow[j + 0]);
            Hrow[j + 1] = fmaf(-lik, wv.y, Hrow[j + 1]);
            Hrow[j + 2] = fmaf(-lik, wv.z, Hrow[j + 2]);
            Hrow[j + 3] = fmaf(-lik, wv.w, Hrow[j + 3]);
          }
        }
      }
      // Keep backward-solve loads from hoisting into the region where Hrow lives
      __builtin_amdgcn_sched_barrier(0);

      // D-scale (per-lane) then backward solve L^T u = y (unit diagonal)
      float u1 = 0.f, u2 = 0.f;
      a1 = y1 * myrd;
      a2 = y2 * myrd;
#pragma unroll
      for (int k = 63; k >= 0; --k) {
        const float t1 = __shfl(a1, k, 64);
        const float t2 = __shfl(a2, k, 64);
        u1 = (i == k) ? t1 : u1;
        u2 = (i == k) ? t2 : u2;
        const float lki = (i < k) ? Lmat[k * LS + i] : 0.0f;
        a1 = fmaf(-lki, t1, a1);
        a2 = fmaf(-lki, t2, a2);
      }

      // Bordered system: dnu = (1^T u1 + r_peq) / (1^T u2); dz = u1 - dnu*u2
      const float sum1 = wave_sum(u1);
      const float sum2 = wave_sum(u2);
      const float dnu = (sum1 + r_peq) * frcp(sum2);
      const float dz = fmaf(-dnu, u2, u1);

      const float dl1 = (l1 * (rp1 + dz) - rc1) * rs1;
      const float dl2 = (l2 * (rp2 - dz) - rc2) * rs2;
      const float ds1 = -rp1 - dz;
      const float ds2 = -rp2 + dz;

      const float c1m = (dl1 < 0.0f) ? (-l1 * frcp(dl1)) : 1.0f;
      const float c2m = (dl2 < 0.0f) ? (-l2 * frcp(dl2)) : 1.0f;
      const float c3m = (ds1 < 0.0f) ? (-s1 * frcp(ds1)) : 1.0f;
      const float c4m = (ds2 < 0.0f) ? (-s2 * frcp(ds2)) : 1.0f;
      const float am = wave_min(fminf(fminf(c1m, c2m), fminf(c3m, c4m)));
      const float a = 0.99f * fminf(1.0f, am);

      z = fmaf(a, dz, z);
      s1 = fmaf(a, ds1, s1);
      s2 = fmaf(a, ds2, s2);
      l1 = fmaf(a, dl1, l1);
      l2 = fmaf(a, dl2, l2);
      nu = fmaf(a, dnu, nu);
      __syncthreads();   // protect Lmat/colbuf/bcast before next iteration rewrites
    }

    x += z;   // ALPHA=1; lam carried in reference but never read
    d = z;
  }

  out[b * 64 + i] = x + d;   // reference returns x + d
}

extern "C" void kernel_launch(void* const* d_in, const int* in_sizes, int n_in,
                              void* d_out, int out_size, void* d_ws, size_t ws_size,
                              hipStream_t stream) {
  const float* c = (const float*)d_in[0];   // (B, 64) f32
  const float* Q = (const float*)d_in[1];   // (64, 64) f32
  float* out = (float*)d_out;               // (B, 64) f32
  const int B = in_sizes[0] / 64;
  hipLaunchKernelGGL(sqp_solve_kernel, dim3(B), dim3(64), 0, stream, c, Q, out);
}

// Round 4
// 1464.986 us; speedup vs baseline: 12.3949x; 1.0976x over previous
//
#include <hip/hip_runtime.h>

// FixedPtSQP: 1024 independent SQP solves, N=64, M_IN=128 (G=[I;-I]), M_EQ=1 (A=1^T).
// One wave per batch element; lane i owns row i of H = Q + diag(dd).
// R3: wavefront-synchronous — a 64-thread block is ONE wave, so all
// __syncthreads are removed (DS ops complete in-order per wave; compiler's
// alias-driven lgkmcnt waits give write->read ordering). Factor loop
// restructured: EARLY next-column LDS write so trailing-update FMAs hide the
// write->read round trip; pivot comes from the LDS broadcast (no shfl);
// per-lane pivot captured at write time (no rldiag array). Q*z and sum(z)
// tracked incrementally via Q u = r - dd*u (H u = r), deleting the per-step
// matvec. Solve vectors need no capture selects: masked multipliers freeze
// each lane's value once its pivot passes.

#define QS 68   // Q row stride in LDS floats (rows 16B-aligned for b128 reads)
#define LS 65   // L row stride: conflict-free by row and by column

__device__ __forceinline__ float frcp(float x) { return __builtin_amdgcn_rcpf(x); }

__device__ __forceinline__ float wave_sum(float v) {
#pragma unroll
  for (int o = 32; o > 0; o >>= 1) v += __shfl_xor(v, o, 64);
  return v;
}
__device__ __forceinline__ float wave_min(float v) {
#pragma unroll
  for (int o = 32; o > 0; o >>= 1) v = fminf(v, __shfl_xor(v, o, 64));
  return v;
}

__global__ __launch_bounds__(64, 1) void sqp_solve_kernel(
    const float* __restrict__ C, const float* __restrict__ Q,
    float* __restrict__ out) {
  const int b = blockIdx.x;
  const int i = threadIdx.x;  // lane == row index

  __shared__ __align__(16) float Qlds[64 * QS];   // pristine Q
  __shared__ __align__(16) float Lmat[64 * LS];   // unit-lower L (strictly lower used)
  __shared__ __align__(16) float colbuf[2][64];   // unscaled column, double-buffered
  __shared__ __align__(16) float bcast[64];       // x broadcast (per SQP iter)

  // Stage Q into LDS once (single wave: no barrier needed anywhere below)
#pragma unroll
  for (int j = 0; j < 64; j += 4) {
    const float4 q = *reinterpret_cast<const float4*>(&Q[i * 64 + j]);
    *reinterpret_cast<float4*>(&Qlds[i * QS + j]) = q;
  }
  const float ci = C[b * 64 + i];

  float x = 0.5f;   // x0
  float d = 0.0f;   // last QP primal step

#pragma unroll 1
  for (int sqp = 0; sqp < 6; ++sqp) {   // MAX_ITER1 + MAX_ITER2, ALPHA=1
    // p = Q0 x - c  (Q0 symmetric)
    bcast[i] = x;
    float p = -ci;
#pragma unroll
    for (int j = 0; j < 64; j += 4) {
      const float4 q = *reinterpret_cast<const float4*>(&Qlds[i * QS + j]);
      const float4 xv = *reinterpret_cast<const float4*>(&bcast[j]);
      p = fmaf(q.x, xv.x, p); p = fmaf(q.y, xv.y, p);
      p = fmaf(q.z, xv.z, p); p = fmaf(q.w, xv.w, p);
    }
    const float h1 = 1.0f - x;
    const float h2 = x;
    const float beq = 1.0f - wave_sum(x);

    float z = 0.f, s1 = 1.f, s2 = 1.f, l1 = 1.f, l2 = 1.f, nu = 0.f;
    float Qz = 0.f;   // tracked Q·z (per lane); z starts at 0
    float Sz = 0.f;   // tracked sum(z) (uniform)

#pragma unroll 1
    for (int it = 0; it < 15; ++it) {   // NEWTON_ITERS
      const float mu = 0.1f * wave_sum(fmaf(s1, l1, s2 * l2)) * (1.0f / 128.0f);

      // Fresh H row (Q part only; dd folded in at column-write time, row==col)
      float Hrow[64];
#pragma unroll
      for (int j = 0; j < 64; j += 4) {
        const float4 q = *reinterpret_cast<const float4*>(&Qlds[i * QS + j]);
        Hrow[j + 0] = q.x; Hrow[j + 1] = q.y; Hrow[j + 2] = q.z; Hrow[j + 3] = q.w;
      }

      const float rs1 = frcp(s1), rs2 = frcp(s2);
      const float r_dual = Qz + p + (l1 - l2) + nu;
      const float rp1 = z + s1 - h1;
      const float rp2 = -z + s2 - h2;
      const float r_peq = Sz - beq;
      const float rc1 = fmaf(l1, s1, -mu);
      const float rc2 = fmaf(l2, s2, -mu);
      const float dd = fmaf(l1, rs1, l2 * rs2);   // > 0; pivots >= 1 (Q0 >= I)
      const float w1 = (l1 * rp1 - rc1) * rs1;
      const float w2 = (l2 * rp2 - rc2) * rs2;
      const float rhs = -(r_dual + w1 - w2);

      // Seed column 0 (dd only at row 0); lane i keeps its own final pivot
      float mypivot = (i == 0) ? Hrow[0] + dd : Hrow[0];
      colbuf[0][i] = mypivot;   // for i>0 this is just H[i][0]; pivot overwritten later

      float a1 = rhs, a2 = 1.0f;   // forward-solve accumulators (freeze at lane's pivot)

      // In-place LDL^T with fused forward solve; NO barriers (single wave).
#pragma unroll
      for (int k = 0; k < 64; ++k) {
        const float* cb = colbuf[k & 1];
        float cw[64];   // broadcast copy of column k (entries k..63 valid)
#pragma unroll
        for (int g = (k >> 2); g < 16; ++g) {
          const float4 t = *reinterpret_cast<const float4*>(&cb[4 * g]);
          cw[4 * g + 0] = t.x; cw[4 * g + 1] = t.y;
          cw[4 * g + 2] = t.z; cw[4 * g + 3] = t.w;
        }
        const float rd = frcp(cw[k]);      // pivot d_k (includes dd), uniform
        const float lik = Hrow[k] * rd;    // L[i][k] (meaningful for i>k)
        if (k < 63) {
          // EARLY write of column k+1 so the round trip hides under the FMAs below
          const float wn = fmaf(-lik, cw[k + 1], Hrow[k + 1]);
          const float wnd = (i == k + 1) ? wn + dd : wn;
          mypivot = (i == k + 1) ? wnd : mypivot;
          colbuf[(k + 1) & 1][i] = wnd;
          Hrow[k + 1] = wn;
          Lmat[i * LS + k] = lik;          // column 63 never read -> skip at k=63
        }
        // fused forward step (unit-diagonal L); lanes i<=k frozen (zero multiplier)
        const float t1 = __shfl(a1, k, 64);
        const float t2 = __shfl(a2, k, 64);
        const float likm = (i > k) ? lik : 0.0f;
        a1 = fmaf(-likm, t1, a1);
        a2 = fmaf(-likm, t2, a2);
        // trailing update j in [k+2, 64)  (j=k+1 handled above; j<=k dead)
#pragma unroll
        for (int j = k + 2; j < 64; ++j)
          Hrow[j] = fmaf(-lik, cw[j], Hrow[j]);
      }
      // a1,a2 now hold y (L y = rhs / L y2 = 1). D-scale per lane:
      const float myrd = frcp(mypivot);
      a1 *= myrd;
      a2 *= myrd;

      // Backward solve L^T u = a; lanes i>=k frozen (zero multiplier)
#pragma unroll
      for (int k = 63; k >= 1; --k) {
        const float t1 = __shfl(a1, k, 64);
        const float t2 = __shfl(a2, k, 64);
        const float lki = (i < k) ? Lmat[k * LS + i] : 0.0f;
        a1 = fmaf(-lki, t1, a1);
        a2 = fmaf(-lki, t2, a2);
      }
      // a1 = u1, a2 = u2. Dual reduction (interleaved for ILP):
      float su1 = a1, su2 = a2;
#pragma unroll
      for (int o = 32; o > 0; o >>= 1) {
        su1 += __shfl_xor(su1, o, 64);
        su2 += __shfl_xor(su2, o, 64);
      }
      const float dnu = (su1 + r_peq) * frcp(su2);
      const float dz = fmaf(-dnu, a2, a1);

      const float dl1 = (l1 * (rp1 + dz) - rc1) * rs1;
      const float dl2 = (l2 * (rp2 - dz) - rc2) * rs2;
      const float ds1 = -rp1 - dz;
      const float ds2 = -rp2 + dz;

      const float c1m = (dl1 < 0.0f) ? (-l1 * frcp(dl1)) : 1.0f;
      const float c2m = (dl2 < 0.0f) ? (-l2 * frcp(dl2)) : 1.0f;
      const float c3m = (ds1 < 0.0f) ? (-s1 * frcp(ds1)) : 1.0f;
      const float c4m = (ds2 < 0.0f) ? (-s2 * frcp(ds2)) : 1.0f;
      const float am = wave_min(fminf(fminf(c1m, c2m), fminf(c3m, c4m)));
      const float a = 0.99f * fminf(1.0f, am);

      // Incremental trackers: H u = r  =>  Q u = r - dd*u
      const float Qdz = (rhs - dd * a1) - dnu * (1.0f - dd * a2);
      Qz = fmaf(a, Qdz, Qz);
      Sz = fmaf(a, su1 - dnu * su2, Sz);

      z = fmaf(a, dz, z);
      s1 = fmaf(a, ds1, s1);
      s2 = fmaf(a, ds2, s2);
      l1 = fmaf(a, dl1, l1);
      l2 = fmaf(a, dl2, l2);
      nu = fmaf(a, dnu, nu);
    }

    x += z;   // ALPHA=1; lam carried in reference but never read
    d = z;
  }

  out[b * 64 + i] = x + d;   // reference returns x + d
}

extern "C" void kernel_launch(void* const* d_in, const int* in_sizes, int n_in,
                              void* d_out, int out_size, void* d_ws, size_t ws_size,
                              hipStream_t stream) {
  const float* c = (const float*)d_in[0];   // (B, 64) f32
  const float* Q = (const float*)d_in[1];   // (64, 64) f32
  float* out = (float*)d_out;               // (B, 64) f32
  const int B = in_sizes[0] / 64;
  hipLaunchKernelGGL(sqp_solve_kernel, dim3(B), dim3(64), 0, stream, c, Q, out);
}